// Round 1
// baseline (1183.824 us; speedup 1.0000x reference)
//
#include <hip/hip_runtime.h>
#include <cstdint>
#include <cstddef>

typedef unsigned short u16t;
typedef __attribute__((ext_vector_type(8))) short short8;   // 8 x bf16 (4 VGPRs)
typedef __attribute__((ext_vector_type(4))) float float4v;  // MFMA C/D frag

#define NATOMS 50400
#define SSP    7
#define DIN    1008
#define KP     1024     // layer-1 K padded to 32*32
#define GRP    7200     // atoms per species
#define GPAD   7296     // 57 * 128
#define NTILE  57
#define H0D    256
#define H1D    192
#define H2D    160

// ---- workspace byte offsets (all 16B aligned) ----
#define OFF_CNT   0ull
#define OFF_SRC   256ull                 // 7*7296*4 = 204288
#define OFF_X     204544ull              // 7*7296*1024*2 = 104595456
#define OFF_W0T   104800000ull           // 56*256*1024*2 = 29360128
#define OFF_W1T   134160128ull           // 56*192*256*2  = 5505024
#define OFF_W2T   139665152ull           // 56*160*192*2  = 3440640
#define OFF_W3    143105792ull           // 56*160*2      = 17920
// total: 143123712 bytes (~136.5 MiB)

__device__ __forceinline__ u16t f2bf(float f) {
    union { float f; unsigned u; } x; x.f = f;
    unsigned r = x.u + 0x7fffu + ((x.u >> 16) & 1u);   // RNE
    return (u16t)(r >> 16);
}
__device__ __forceinline__ float bf2f(u16t h) {
    return __uint_as_float(((unsigned)h) << 16);
}
__device__ __forceinline__ float celu_f(float x) {
    // celu(x, 0.1) = x>0 ? x : 0.1*(e^{10x}-1)
    return x > 0.f ? x : 0.1f * (__expf(x * 10.f) - 1.f);
}

// ---------------- prep kernels ----------------

// atom -> slot within its species block (order irrelevant: final op is a sum)
__global__ void assign_k(const int* __restrict__ sp, int* __restrict__ cnt,
                         int* __restrict__ src_of) {
    int i = blockIdx.x * 256 + threadIdx.x;
    if (i < NATOMS) {
        int s = sp[i];
        int pos = atomicAdd(&cnt[s], 1);
        src_of[s * GPAD + pos] = i;
    }
}

// gather aev rows into species-sorted bf16 X [7][7296][1024]; pad rows/cols = 0
__global__ void gather_k(const float* __restrict__ aev, const int* __restrict__ src_of,
                         u16t* __restrict__ X) {
    int b = blockIdx.x;            // s*GPAD + row
    int row = b % GPAD;
    int t = threadIdx.x;
    int c = t * 4;
    ushort4 o; o.x = 0; o.y = 0; o.z = 0; o.w = 0;
    if (row < GRP && c < DIN) {
        int i = src_of[b];
        float4 v = *(const float4*)(aev + (size_t)i * DIN + c);
        o.x = f2bf(v.x); o.y = f2bf(v.y); o.z = f2bf(v.z); o.w = f2bf(v.w);
    }
    *(ushort4*)(X + (size_t)b * KP + c) = o;
}

// src [batch][K_in][C] fp32 -> dst [batch][C][K_out] bf16, zero-fill K_in..K_out
__global__ void transpose_convert_k(const float* __restrict__ src, u16t* __restrict__ dst,
                                    int K_in, int C, int K_out) {
    __shared__ float tile[64][65];
    int b = blockIdx.z;
    int k0 = blockIdx.x * 64, c0 = blockIdx.y * 64;
    int tx = threadIdx.x & 63, ty = threadIdx.x >> 6;   // ty 0..3
    const float* sp = src + (size_t)b * K_in * C;
#pragma unroll
    for (int i = 0; i < 16; ++i) {
        int kl = i * 4 + ty;
        int k = k0 + kl, c = c0 + tx;
        float v = (k < K_in && c < C) ? sp[(size_t)k * C + c] : 0.f;
        tile[kl][tx] = v;
    }
    __syncthreads();
    u16t* dp = dst + (size_t)b * C * K_out;
#pragma unroll
    for (int i = 0; i < 16; ++i) {
        int cl = i * 4 + ty;
        int c = c0 + cl, k = k0 + tx;
        if (c < C && k < K_out)
            dp[(size_t)c * K_out + k] = f2bf(tile[tx][cl]);
    }
}

__global__ void convert_w3_k(const float* __restrict__ src, u16t* __restrict__ dst, int n) {
    int i = blockIdx.x * 256 + threadIdx.x;
    if (i < n) dst[i] = f2bf(src[i]);
}

// ---------------- fused per-(species,model,row-tile) MLP ----------------
// grid (57, 56), 512 threads (8 waves)
__launch_bounds__(512, 2)
__global__ void fused_mlp(const u16t* __restrict__ X, const u16t* __restrict__ W0T,
                          const u16t* __restrict__ W1T, const u16t* __restrict__ W2T,
                          const u16t* __restrict__ W3B,
                          const float* __restrict__ b0, const float* __restrict__ b1,
                          const float* __restrict__ b2, const float* __restrict__ b3,
                          float* __restrict__ out) {
    __shared__ __attribute__((aligned(16))) char lds_stage[24576]; // A 8K + B 16K
    __shared__ __attribute__((aligned(16))) char lds_act0[65536];  // H0 (later H2)
    __shared__ __attribute__((aligned(16))) char lds_act1[49152];  // H1

    const int tid  = threadIdx.x;
    const int w    = tid >> 6;
    const int lane = tid & 63;
    const int l15  = lane & 15;
    const int quad = lane >> 4;          // 0..3
    const int tile = blockIdx.x;         // 0..56
    const int bsm  = blockIdx.y;         // s*8+m
    const int s    = bsm >> 3;

    const u16t* Xp  = X + ((size_t)s * GPAD + (size_t)tile * 128) * KP;
    const u16t* W0p = W0T + (size_t)bsm * H0D * KP;

    // ======== Phase 1: H0 = celu(X[128x1024] @ W0[1024x256] + b0) ========
    float4v acc[4][4];
#pragma unroll
    for (int i = 0; i < 4; ++i)
#pragma unroll
        for (int j = 0; j < 4; ++j) acc[i][j] = (float4v){0.f, 0.f, 0.f, 0.f};

    const int RW = (w & 1) * 64;
    const int CW = (w >> 1) * 64;

    for (int kc = 0; kc < 32; ++kc) {
        const int k0 = kc * 32;
        __syncthreads();
        {
            // A tile [128 x 32]: 512 x 16B units; unit = tid
            int r = tid >> 2, p = tid & 3;
            short8 va = *(const short8*)(Xp + (size_t)r * KP + k0 + p * 8);
            // B tile [256 cols x 32]: 1024 units; units tid and tid+512
            int c1 = tid >> 2, p1 = tid & 3;
            int u2 = tid + 512;
            int c2 = u2 >> 2, p2 = u2 & 3;
            short8 vb1 = *(const short8*)(W0p + (size_t)c1 * KP + k0 + p1 * 8);
            short8 vb2 = *(const short8*)(W0p + (size_t)c2 * KP + k0 + p2 * 8);
            *(short8*)(lds_stage + (r * 4 + ((p ^ (r >> 1)) & 3)) * 16) = va;
            *(short8*)(lds_stage + 8192 + (c1 * 4 + ((p1 ^ (c1 >> 1)) & 3)) * 16) = vb1;
            *(short8*)(lds_stage + 8192 + (c2 * 4 + ((p2 ^ (c2 >> 1)) & 3)) * 16) = vb2;
        }
        __syncthreads();
        short8 af[4], bfv[4];
#pragma unroll
        for (int rt = 0; rt < 4; ++rt) {
            int r = RW + rt * 16 + l15;
            af[rt] = *(const short8*)(lds_stage + (r * 4 + ((quad ^ (r >> 1)) & 3)) * 16);
        }
#pragma unroll
        for (int ct = 0; ct < 4; ++ct) {
            int c = CW + ct * 16 + l15;
            bfv[ct] = *(const short8*)(lds_stage + 8192 + (c * 4 + ((quad ^ (c >> 1)) & 3)) * 16);
        }
#pragma unroll
        for (int rt = 0; rt < 4; ++rt)
#pragma unroll
            for (int ct = 0; ct < 4; ++ct)
                acc[rt][ct] = __builtin_amdgcn_mfma_f32_16x16x32_bf16(af[rt], bfv[ct], acc[rt][ct], 0, 0, 0);
    }
    { // epilogue 1 -> lds_act0 [128][256] bf16, 16B-chunk XOR swizzle (mask 31)
        float bias[4];
#pragma unroll
        for (int ct = 0; ct < 4; ++ct) bias[ct] = b0[bsm * H0D + CW + ct * 16 + l15];
#pragma unroll
        for (int rt = 0; rt < 4; ++rt)
#pragma unroll
            for (int ct = 0; ct < 4; ++ct) {
                int col = CW + ct * 16 + l15;
                int q = col >> 3;
#pragma unroll
                for (int rg = 0; rg < 4; ++rg) {
                    int row = RW + rt * 16 + quad * 4 + rg;
                    float v = celu_f(acc[rt][ct][rg] + bias[ct]);
                    int addr = row * 512 + (((q ^ row) & 31) * 8 + (col & 7)) * 2;
                    *(u16t*)(lds_act0 + addr) = f2bf(v);
                }
            }
    }

    // ======== Phase 2: H1 = celu(H0[128x256] @ W1[256x192] + b1) ========
    float4v acc2[4][3];
#pragma unroll
    for (int i = 0; i < 4; ++i)
#pragma unroll
        for (int j = 0; j < 3; ++j) acc2[i][j] = (float4v){0.f, 0.f, 0.f, 0.f};
    const int RW2 = (w & 1) * 64;
    const int CW2 = (w >> 1) * 48;
    const u16t* W1p = W1T + (size_t)bsm * H1D * H0D;   // [192][256]

    for (int kc = 0; kc < 8; ++kc) {
        const int k0 = kc * 32;
        __syncthreads();
        {
            int c = tid >> 2, p = tid & 3;             // 768 units total
            short8 vb = *(const short8*)(W1p + (size_t)c * H0D + k0 + p * 8);
            *(short8*)(lds_stage + (c * 4 + ((p ^ (c >> 1)) & 3)) * 16) = vb;
            if (tid < 256) {
                int u2 = tid + 512;
                int c2 = u2 >> 2, p2 = u2 & 3;
                short8 vb2 = *(const short8*)(W1p + (size_t)c2 * H0D + k0 + p2 * 8);
                *(short8*)(lds_stage + (c2 * 4 + ((p2 ^ (c2 >> 1)) & 3)) * 16) = vb2;
            }
        }
        __syncthreads();
        short8 af[4], bfv[3];
#pragma unroll
        for (int rt = 0; rt < 4; ++rt) {
            int r = RW2 + rt * 16 + l15;
            int q = kc * 4 + quad;
            af[rt] = *(const short8*)(lds_act0 + r * 512 + ((q ^ r) & 31) * 16);
        }
#pragma unroll
        for (int ct = 0; ct < 3; ++ct) {
            int c = CW2 + ct * 16 + l15;
            bfv[ct] = *(const short8*)(lds_stage + (c * 4 + ((quad ^ (c >> 1)) & 3)) * 16);
        }
#pragma unroll
        for (int rt = 0; rt < 4; ++rt)
#pragma unroll
            for (int ct = 0; ct < 3; ++ct)
                acc2[rt][ct] = __builtin_amdgcn_mfma_f32_16x16x32_bf16(af[rt], bfv[ct], acc2[rt][ct], 0, 0, 0);
    }
    { // epilogue 2 -> lds_act1 [128][192] bf16, chunk swizzle (low 3 bits)
        float bias[3];
#pragma unroll
        for (int ct = 0; ct < 3; ++ct) bias[ct] = b1[bsm * H1D + CW2 + ct * 16 + l15];
#pragma unroll
        for (int rt = 0; rt < 4; ++rt)
#pragma unroll
            for (int ct = 0; ct < 3; ++ct) {
                int col = CW2 + ct * 16 + l15;
                int q = col >> 3;
#pragma unroll
                for (int rg = 0; rg < 4; ++rg) {
                    int row = RW2 + rt * 16 + quad * 4 + rg;
                    float v = celu_f(acc2[rt][ct][rg] + bias[ct]);
                    int qs = (q & ~7) | ((q ^ row) & 7);
                    int addr = row * 384 + (qs * 8 + (col & 7)) * 2;
                    *(u16t*)(lds_act1 + addr) = f2bf(v);
                }
            }
    }

    // ======== Phase 3: H2 = celu(H1[128x192] @ W2[192x160] + b2) ========
    float4v acc3[2][5];
#pragma unroll
    for (int i = 0; i < 2; ++i)
#pragma unroll
        for (int j = 0; j < 5; ++j) acc3[i][j] = (float4v){0.f, 0.f, 0.f, 0.f};
    const int RW3 = (w & 3) * 32;
    const int CW3 = (w >> 2) * 80;
    const u16t* W2p = W2T + (size_t)bsm * H2D * H1D;   // [160][192]

    for (int kc = 0; kc < 6; ++kc) {
        const int k0 = kc * 32;
        __syncthreads();
        {
            int c = tid >> 2, p = tid & 3;             // 640 units total
            short8 vb = *(const short8*)(W2p + (size_t)c * H1D + k0 + p * 8);
            *(short8*)(lds_stage + (c * 4 + ((p ^ (c >> 1)) & 3)) * 16) = vb;
            if (tid < 128) {
                int u2 = tid + 512;
                int c2 = u2 >> 2, p2 = u2 & 3;
                short8 vb2 = *(const short8*)(W2p + (size_t)c2 * H1D + k0 + p2 * 8);
                *(short8*)(lds_stage + (c2 * 4 + ((p2 ^ (c2 >> 1)) & 3)) * 16) = vb2;
            }
        }
        __syncthreads();
        short8 af[2], bfv[5];
#pragma unroll
        for (int rt = 0; rt < 2; ++rt) {
            int r = RW3 + rt * 16 + l15;
            int q = kc * 4 + quad;
            int qs = (q & ~7) | ((q ^ r) & 7);
            af[rt] = *(const short8*)(lds_act1 + r * 384 + qs * 16);
        }
#pragma unroll
        for (int ct = 0; ct < 5; ++ct) {
            int c = CW3 + ct * 16 + l15;
            bfv[ct] = *(const short8*)(lds_stage + (c * 4 + ((quad ^ (c >> 1)) & 3)) * 16);
        }
#pragma unroll
        for (int rt = 0; rt < 2; ++rt)
#pragma unroll
            for (int ct = 0; ct < 5; ++ct)
                acc3[rt][ct] = __builtin_amdgcn_mfma_f32_16x16x32_bf16(af[rt], bfv[ct], acc3[rt][ct], 0, 0, 0);
    }
    { // epilogue 3 -> H2 into lds_act0 (plain [128][160] bf16; phase-3 never reads act0)
        float bias[5];
#pragma unroll
        for (int ct = 0; ct < 5; ++ct) bias[ct] = b2[bsm * H2D + CW3 + ct * 16 + l15];
#pragma unroll
        for (int rt = 0; rt < 2; ++rt)
#pragma unroll
            for (int ct = 0; ct < 5; ++ct) {
                int col = CW3 + ct * 16 + l15;
#pragma unroll
                for (int rg = 0; rg < 4; ++rg) {
                    int row = RW3 + rt * 16 + quad * 4 + rg;
                    float v = celu_f(acc3[rt][ct][rg] + bias[ct]);
                    *(u16t*)(lds_act0 + (row * H2D + col) * 2) = f2bf(v);
                }
            }
    }
    __syncthreads();

    // ======== Phase 4: e = H2 @ W3 + b3 ; masked sum ; /8 for ensemble mean ====
    if (tid < 128) {
        const int row = tid;
        const u16t* w3 = W3B + bsm * H2D;
        float e = b3[bsm];
#pragma unroll 8
        for (int k = 0; k < H2D; ++k)
            e += bf2f(*(const u16t*)(lds_act0 + (row * H2D + k) * 2)) * bf2f(w3[k]);
        int grow = tile * 128 + row;
        float v = (grow < GRP) ? e * 0.125f : 0.f;
#pragma unroll
        for (int off = 32; off; off >>= 1) v += __shfl_down(v, off);
        if ((tid & 63) == 0) atomicAdd(out, v);
    }
}

// ---------------- host launch ----------------
extern "C" void kernel_launch(void* const* d_in, const int* in_sizes, int n_in,
                              void* d_out, int out_size, void* d_ws, size_t ws_size,
                              hipStream_t stream) {
    const int*   species = (const int*)d_in[0];
    const float* aev     = (const float*)d_in[1];
    const float* W0      = (const float*)d_in[2];
    const float* b0      = (const float*)d_in[3];
    const float* W1      = (const float*)d_in[4];
    const float* b1      = (const float*)d_in[5];
    const float* W2      = (const float*)d_in[6];
    const float* b2      = (const float*)d_in[7];
    const float* W3      = (const float*)d_in[8];
    const float* b3      = (const float*)d_in[9];
    float* out = (float*)d_out;
    char*  ws  = (char*)d_ws;

    int*  cnt    = (int*)(ws + OFF_CNT);
    int*  src_of = (int*)(ws + OFF_SRC);
    u16t* X      = (u16t*)(ws + OFF_X);
    u16t* W0T    = (u16t*)(ws + OFF_W0T);
    u16t* W1T    = (u16t*)(ws + OFF_W1T);
    u16t* W2T    = (u16t*)(ws + OFF_W2T);
    u16t* W3B    = (u16t*)(ws + OFF_W3);

    hipMemsetAsync(cnt, 0, 32, stream);
    hipMemsetAsync(d_out, 0, sizeof(float), stream);

    assign_k<<<(NATOMS + 255) / 256, 256, 0, stream>>>(species, cnt, src_of);
    gather_k<<<SSP * GPAD, 256, 0, stream>>>(aev, src_of, X);
    transpose_convert_k<<<dim3(16, 4, 56), 256, 0, stream>>>(W0, W0T, DIN, H0D, KP);
    transpose_convert_k<<<dim3(4, 3, 56), 256, 0, stream>>>(W1, W1T, H0D, H1D, H0D);
    transpose_convert_k<<<dim3(3, 3, 56), 256, 0, stream>>>(W2, W2T, H1D, H2D, H1D);
    convert_w3_k<<<(56 * H2D + 255) / 256, 256, 0, stream>>>(W3, W3B, 56 * H2D);

    fused_mlp<<<dim3(NTILE, 56), 512, 0, stream>>>(X, W0T, W1T, W2T, W3B,
                                                   b0, b1, b2, b3, out);
}